// Round 8
// baseline (31.896 us; speedup 1.0000x reference)
//
#include <hip/hip_runtime.h>
#include <hip/hip_fp16.h>

#define FDIM 1024
#define KNZ 32
#define NROWS 2048
#define RB 8          // rows per block
#define TPB 1024      // threads per block == FDIM (o = tid)
#define EPSV 1e-6f

static_assert(TPB == FDIM, "o = tid mapping requires TPB == FDIM");
static_assert(NROWS % RB == 0, "rows divide");

// granule swizzle: spreads structured f-sequences across the 8 bank-quads
__device__ __forceinline__ unsigned int swz(unsigned int i) {
  return i ^ ((i >> 3) & 7u);
}

__device__ __forceinline__ unsigned f16bits(float f) {
  return (unsigned)__half_as_ushort(__float2half(f));
}

// Table entry: [31:16] = f16 weight bits, [9:0] = swizzled granule offset.
// Prep also BANK-SCHEDULES each o's 32 entries: counting-sort by bank-quad
// (off&7), then emit cyclically starting at quad (o&7) — so at gather step j
// the 64 lanes of a wave hit quads (lane+j)&7: ~8 lanes/quad instead of a
// random max of ~13. Summation order is commutative, main kernel unchanged.
__global__ void geo_prep(const int* __restrict__ idx,
                         const float* __restrict__ w1,
                         const float* __restrict__ w2,
                         unsigned* __restrict__ pr1, unsigned* __restrict__ pr2) {
  __shared__ unsigned short kord[64][33];  // per-thread quad-sorted k list
  __shared__ int cnt[64][9];
  __shared__ int ptr[64][9];
  __shared__ int rem[64][9];
  const int t = threadIdx.x;            // 64 threads, one o each
  const int o = blockIdx.x * 64 + t;    // 16 blocks

  #pragma unroll
  for (int q = 0; q < 8; ++q) cnt[t][q] = 0;

  // pass 1: count per quad (idx row is 128 B -> L1-resident for re-reads)
  #pragma unroll
  for (int k = 0; k < KNZ; ++k) {
    unsigned off = swz((unsigned)idx[o * KNZ + k]);
    ++cnt[t][off & 7u];
  }
  // prefix -> segment starts
  {
    int s = 0;
    #pragma unroll
    for (int q = 0; q < 8; ++q) { ptr[t][q] = s; s += cnt[t][q]; }
  }
  // pass 2: place k's into quad segments
  #pragma unroll
  for (int k = 0; k < KNZ; ++k) {
    unsigned off = swz((unsigned)idx[o * KNZ + k]);
    kord[t][ptr[t][off & 7u]++] = (unsigned short)k;
  }
  // rebuild starts + remaining counts
  {
    int s = 0;
    #pragma unroll
    for (int q = 0; q < 8; ++q) {
      int c = cnt[t][q];
      ptr[t][q] = s; rem[t][q] = c; s += c;
    }
  }
  // emit in cyclic quad order; slot j is the gather step
  int qq = t & 7;
  for (int j = 0; j < KNZ; ++j) {
    while (rem[t][qq] == 0) qq = (qq + 1) & 7;
    int k = kord[t][ptr[t][qq]++];
    --rem[t][qq];
    qq = (qq + 1) & 7;
    unsigned off = swz((unsigned)idx[o * KNZ + k]);
    pr1[j * FDIM + o] = (f16bits(w1[o * KNZ + k]) << 16) | off;
    pr2[j * FDIM + o] = (f16bits(w2[o * KNZ + k]) << 16) | off;
  }
}

// f16 gather: 4x v_pk_fma_f16, ~8 VALU ops total (vs ~18 for bf16 unpack)
__device__ __forceinline__ void gatherh(unsigned e, const uint4* lds,
                                        __half2* acc2) {
  unsigned wd = (e & 0xFFFF0000u) | (e >> 16);        // dup f16 weight
  __half2 w = *reinterpret_cast<__half2*>(&wd);
  uint4 hv = lds[e & 1023u];                          // ds_read_b128: 8 rows
  const unsigned* hd = reinterpret_cast<const unsigned*>(&hv);
  #pragma unroll
  for (int d = 0; d < 4; ++d) {
    __half2 h2 = *reinterpret_cast<const __half2*>(&hd[d]);
    acc2[d] = __hfma2(h2, w, acc2[d]);
  }
}

template <bool TR>
__global__ __launch_bounds__(TPB, 4)
void geo_main(const float* __restrict__ x, const float* __restrict__ norm_w,
              const float* __restrict__ b1, const float* __restrict__ amp,
              const float* __restrict__ freq, const float* __restrict__ decay,
              const float* __restrict__ b2, const float* __restrict__ alpha,
              const unsigned* __restrict__ pr1, const unsigned* __restrict__ pr2,
              const int* __restrict__ idx, const float* __restrict__ w1,
              const float* __restrict__ w2, float* __restrict__ out) {
  // granule f holds rows 0..7 of feature f as 8 f16 (dword d = rows 2d|2d+1)
  __shared__ uint4 h_lds[FDIM];            // 16 KB, holds g*x (rs applied later)
  __shared__ uint4 s_lds[FDIM];            // 16 KB
  __shared__ float red[(TPB / 64) * RB];   // per-wave row partials
  __shared__ float rs_sh[RB];              // final rs per row

  const int tid = threadIdx.x;
  const int lane = tid & 63;
  const int wid = tid >> 6;
  const int r0 = blockIdx.x * RB;
  const int o = tid;

  // ---------- Phase A: load x; write g*x (f16) transposed; wave partials ----------
  {
    float v[RB];
    #pragma unroll
    for (int r = 0; r < RB; ++r)
      v[r] = x[(r0 + r) * FDIM + tid];     // coalesced per row

    const float g = norm_w[tid];

    // log-row-halving reduce: 17 shfl instead of 48.
    float p[RB];
    #pragma unroll
    for (int r = 0; r < RB; ++r) p[r] = v[r] * v[r];
    #pragma unroll
    for (int r = 0; r < 4; ++r) {
      float up = __shfl_xor(p[r + 4], 4, 64);
      float dn = __shfl_xor(p[r], 4, 64);
      p[r] = (lane & 4) ? (p[r + 4] + up) : (p[r] + dn);
    }
    #pragma unroll
    for (int r = 0; r < 2; ++r) {
      float up = __shfl_xor(p[r + 2], 2, 64);
      float dn = __shfl_xor(p[r], 2, 64);
      p[r] = (lane & 2) ? (p[r + 2] + up) : (p[r] + dn);
    }
    {
      float up = __shfl_xor(p[1], 1, 64);
      float dn = __shfl_xor(p[0], 1, 64);
      p[0] = (lane & 1) ? (p[1] + up) : (p[0] + dn);
    }
    p[0] += __shfl_xor(p[0], 8, 64);
    p[0] += __shfl_xor(p[0], 16, 64);
    p[0] += __shfl_xor(p[0], 32, 64);
    if (lane < RB) red[wid * RB + lane] = p[0];  // red[w*8 + row]

    uint4 h;
    __half2 h01 = __floats2half2_rn(g * v[0], g * v[1]);
    __half2 h23 = __floats2half2_rn(g * v[2], g * v[3]);
    __half2 h45 = __floats2half2_rn(g * v[4], g * v[5]);
    __half2 h67 = __floats2half2_rn(g * v[6], g * v[7]);
    h.x = *reinterpret_cast<unsigned*>(&h01);
    h.y = *reinterpret_cast<unsigned*>(&h23);
    h.z = *reinterpret_cast<unsigned*>(&h45);
    h.w = *reinterpret_cast<unsigned*>(&h67);
    h_lds[swz((unsigned)tid)] = h;         // conflict-free under swz
  }  // v, p dead here

  __syncthreads();                          // barrier #1

  // every wave redundantly folds the 16 wave-partials and writes the SAME
  // rs_sh[0..7]; own-wave program order guarantees visibility at the epilogue.
  {
    float a = red[lane] + red[64 + lane];   // red[w*8+row]: w = lane>>3, 8+(lane>>3)
    a += __shfl_xor(a, 8, 64);
    a += __shfl_xor(a, 16, 64);
    a += __shfl_xor(a, 32, 64);
    if (lane < RB) rs_sh[lane] = rsqrtf(a * (1.0f / FDIM) + EPSV);
  }

  // ---------- Stage 1: acc = gather(g*x)·w1 (f16 packed) ----------
  __half2 acc2[4];
  {
    unsigned z = 0;
    #pragma unroll
    for (int d = 0; d < 4; ++d) acc2[d] = *reinterpret_cast<__half2*>(&z);
  }

  if (TR) {
    #pragma unroll
    for (int gk = 0; gk < 4; ++gk) {
      unsigned u[8];                        // transient: 8 loads in flight
      #pragma unroll
      for (int j = 0; j < 8; ++j) u[j] = pr1[(gk * 8 + j) * FDIM + o];
      #pragma unroll
      for (int j = 0; j < 8; ++j) gatherh(u[j], h_lds, acc2);
    }
  } else {
    #pragma unroll 8
    for (int k = 0; k < KNZ; ++k) {
      unsigned off = swz((unsigned)idx[o * KNZ + k]);
      unsigned e = (f16bits(w1[o * KNZ + k]) << 16) | off;
      gatherh(e, h_lds, acc2);
    }
  }

  // epilogue 1: z = rs*acc + b1 ; s = amp*sin(freq z)*exp(-decay z^2)
  {
    const float bb1 = b1[o], am = amp[o], fq = freq[o], dc = decay[o];
    const float4 ra = *reinterpret_cast<const float4*>(&rs_sh[0]);  // broadcast
    const float4 rb = *reinterpret_cast<const float4*>(&rs_sh[4]);
    const float rsv[RB] = {ra.x, ra.y, ra.z, ra.w, rb.x, rb.y, rb.z, rb.w};
    float accf[RB];
    #pragma unroll
    for (int d = 0; d < 4; ++d) {
      float2 f = __half22float2(acc2[d]);
      accf[2 * d] = f.x; accf[2 * d + 1] = f.y;
    }
    float s[RB];
    #pragma unroll
    for (int r = 0; r < RB; ++r) {
      float z = fmaf(accf[r], rsv[r], bb1);
      s[r] = am * __sinf(fq * z) * __expf(-dc * z * z);
    }
    uint4 sv;
    __half2 s01 = __floats2half2_rn(s[0], s[1]);
    __half2 s23 = __floats2half2_rn(s[2], s[3]);
    __half2 s45 = __floats2half2_rn(s[4], s[5]);
    __half2 s67 = __floats2half2_rn(s[6], s[7]);
    sv.x = *reinterpret_cast<unsigned*>(&s01);
    sv.y = *reinterpret_cast<unsigned*>(&s23);
    sv.z = *reinterpret_cast<unsigned*>(&s45);
    sv.w = *reinterpret_cast<unsigned*>(&s67);
    s_lds[swz((unsigned)o)] = sv;          // conflict-free under swz
  }
  __syncthreads();                          // barrier #2

  // ---------- Stage 2: h2 = gather(s)·w2 + b2 ; out = x + alpha*h2 ----------
  {
    unsigned z = 0;
    #pragma unroll
    for (int d = 0; d < 4; ++d) acc2[d] = *reinterpret_cast<__half2*>(&z);
  }

  if (TR) {
    #pragma unroll
    for (int gk = 0; gk < 4; ++gk) {
      unsigned u[8];
      #pragma unroll
      for (int j = 0; j < 8; ++j) u[j] = pr2[(gk * 8 + j) * FDIM + o];
      #pragma unroll
      for (int j = 0; j < 8; ++j) gatherh(u[j], s_lds, acc2);
    }
  } else {
    #pragma unroll 8
    for (int k = 0; k < KNZ; ++k) {
      unsigned off = swz((unsigned)idx[o * KNZ + k]);
      unsigned e = (f16bits(w2[o * KNZ + k]) << 16) | off;
      gatherh(e, s_lds, acc2);
    }
  }

  {
    const float bb2 = b2[o];
    const float al = alpha[0];
    float accf[RB];
    #pragma unroll
    for (int d = 0; d < 4; ++d) {
      float2 f = __half22float2(acc2[d]);
      accf[2 * d] = f.x; accf[2 * d + 1] = f.y;
    }
    #pragma unroll
    for (int r = 0; r < RB; ++r)
      out[(r0 + r) * FDIM + o] =
          fmaf(al, accf[r] + bb2, x[(r0 + r) * FDIM + o]);  // x re-read: L2-warm
  }
}

extern "C" void kernel_launch(void* const* d_in, const int* in_sizes, int n_in,
                              void* d_out, int out_size, void* d_ws, size_t ws_size,
                              hipStream_t stream) {
  const float* x      = (const float*)d_in[0];
  const int*   idx    = (const int*)d_in[1];
  const float* norm_w = (const float*)d_in[2];
  const float* w1     = (const float*)d_in[3];
  const float* b1     = (const float*)d_in[4];
  const float* amp    = (const float*)d_in[5];
  const float* freq   = (const float*)d_in[6];
  const float* decay  = (const float*)d_in[7];
  const float* w2     = (const float*)d_in[8];
  const float* b2     = (const float*)d_in[9];
  const float* alpha  = (const float*)d_in[10];
  float* out = (float*)d_out;

  const size_t need = 2ull * FDIM * KNZ * sizeof(unsigned);  // 256 KB
  if (ws_size >= need) {
    unsigned* pr1 = (unsigned*)d_ws;
    unsigned* pr2 = pr1 + (size_t)FDIM * KNZ;
    geo_prep<<<FDIM / 64, 64, 0, stream>>>(idx, w1, w2, pr1, pr2);
    geo_main<true><<<NROWS / RB, TPB, 0, stream>>>(
        x, norm_w, b1, amp, freq, decay, b2, alpha, pr1, pr2, idx, w1, w2, out);
  } else {
    geo_main<false><<<NROWS / RB, TPB, 0, stream>>>(
        x, norm_w, b1, amp, freq, decay, b2, alpha, nullptr, nullptr, idx, w1, w2, out);
  }
}

// Round 9
// 19.845 us; speedup vs baseline: 1.6073x; 1.6073x over previous
//
#include <hip/hip_runtime.h>
#include <hip/hip_fp16.h>

#define FDIM 1024
#define KNZ 32
#define NROWS 2048
#define RB 8          // rows per block
#define TPB 1024      // threads per block == FDIM (o = tid)
#define EPSV 1e-6f

static_assert(TPB == FDIM, "o = tid mapping requires TPB == FDIM");
static_assert(NROWS % RB == 0, "rows divide");

// granule swizzle: spreads structured f-sequences across the 8 bank-quads
__device__ __forceinline__ unsigned int swz(unsigned int i) {
  return i ^ ((i >> 3) & 7u);
}

__device__ __forceinline__ unsigned f16bits(float f) {
  return (unsigned)__half_as_ushort(__float2half(f));
}

// Table entry: [31:16] = f16 weight bits, [9:0] = swizzled granule offset.
//
// BANK-BALANCED SCHEDULE, fully parallel: one thread per (o,k). Within each
// 32-thread o-group, ballot-derived per-quad masks give each entry its rank r
// within its bank-quad; emission position = lexicographic rank of the key
// (r, (quad-o)&7). Result: at gather step j the main kernel's 64 lanes target
// quads ~(o+j)&7 -> ~8 lanes/quad, the conflict-free minimum for b128 reads.
// Summation reorder is exact (fp add order changes only).
__global__ void geo_prep(const int* __restrict__ idx,
                         const float* __restrict__ w1,
                         const float* __restrict__ w2,
                         unsigned* __restrict__ pr1, unsigned* __restrict__ pr2) {
  const int tid = threadIdx.x;               // 256 threads
  const int lane = tid & 63;
  const int grp = (lane >> 5);               // which 32-half of the wave
  const int k = tid & 31;
  const int o = blockIdx.x * 8 + (tid >> 5); // 8 outputs per block

  const unsigned off = swz((unsigned)idx[o * KNZ + k]);  // coalesced
  const int q = (int)(off & 7u);
  const int ob = o & 7;
  const int qr = (q - ob) & 7;               // relative quad (cyclic start o&7)

  const unsigned long long gmask = 0xFFFFFFFFull << (32 * grp);
  const unsigned long long lowmask = (1ull << lane) - 1ull;

  // per-quad membership masks of my 32-entry group
  unsigned long long m[8];
  #pragma unroll
  for (int qq = 0; qq < 8; ++qq) m[qq] = __ballot(q == qq) & gmask;

  // my rank within my quad (static-index select, no scratch)
  unsigned long long mym = 0;
  #pragma unroll
  for (int qq = 0; qq < 8; ++qq) mym = (q == qq) ? m[qq] : mym;
  const int r = __popcll(mym & lowmask);

  // position = #entries with key (r', qr') < (r, qr) lexicographic
  int pos = 0;
  #pragma unroll
  for (int qq = 0; qq < 8; ++qq) {
    const int c = (int)__popcll(m[qq]);
    const int qqr = (qq - ob) & 7;
    pos += (r < c) ? r : c;                  // ranks 0..r-1 in quad qq
    pos += (qqr < qr && c > r) ? 1 : 0;      // rank-r entry in earlier quad
  }

  const unsigned e1 = (f16bits(w1[o * KNZ + k]) << 16) | off;
  const unsigned e2 = (f16bits(w2[o * KNZ + k]) << 16) | off;
  pr1[pos * FDIM + o] = e1;
  pr2[pos * FDIM + o] = e2;
}

// f16 gather: 4x v_pk_fma_f16, ~8 VALU ops total (vs ~18 for bf16 unpack)
__device__ __forceinline__ void gatherh(unsigned e, const uint4* lds,
                                        __half2* acc2) {
  unsigned wd = (e & 0xFFFF0000u) | (e >> 16);        // dup f16 weight
  __half2 w = *reinterpret_cast<__half2*>(&wd);
  uint4 hv = lds[e & 1023u];                          // ds_read_b128: 8 rows
  const unsigned* hd = reinterpret_cast<const unsigned*>(&hv);
  #pragma unroll
  for (int d = 0; d < 4; ++d) {
    __half2 h2 = *reinterpret_cast<const __half2*>(&hd[d]);
    acc2[d] = __hfma2(h2, w, acc2[d]);
  }
}

template <bool TR>
__global__ __launch_bounds__(TPB, 4)
void geo_main(const float* __restrict__ x, const float* __restrict__ norm_w,
              const float* __restrict__ b1, const float* __restrict__ amp,
              const float* __restrict__ freq, const float* __restrict__ decay,
              const float* __restrict__ b2, const float* __restrict__ alpha,
              const unsigned* __restrict__ pr1, const unsigned* __restrict__ pr2,
              const int* __restrict__ idx, const float* __restrict__ w1,
              const float* __restrict__ w2, float* __restrict__ out) {
  // granule f holds rows 0..7 of feature f as 8 f16 (dword d = rows 2d|2d+1)
  __shared__ uint4 h_lds[FDIM];            // 16 KB, holds g*x (rs applied later)
  __shared__ uint4 s_lds[FDIM];            // 16 KB
  __shared__ float red[(TPB / 64) * RB];   // per-wave row partials
  __shared__ float rs_sh[RB];              // final rs per row

  const int tid = threadIdx.x;
  const int lane = tid & 63;
  const int wid = tid >> 6;
  const int r0 = blockIdx.x * RB;
  const int o = tid;

  // ---------- Phase A: load x; write g*x (f16) transposed; wave partials ----------
  {
    float v[RB];
    #pragma unroll
    for (int r = 0; r < RB; ++r)
      v[r] = x[(r0 + r) * FDIM + tid];     // coalesced per row

    const float g = norm_w[tid];

    // log-row-halving reduce: 17 shfl instead of 48.
    float p[RB];
    #pragma unroll
    for (int r = 0; r < RB; ++r) p[r] = v[r] * v[r];
    #pragma unroll
    for (int r = 0; r < 4; ++r) {
      float up = __shfl_xor(p[r + 4], 4, 64);
      float dn = __shfl_xor(p[r], 4, 64);
      p[r] = (lane & 4) ? (p[r + 4] + up) : (p[r] + dn);
    }
    #pragma unroll
    for (int r = 0; r < 2; ++r) {
      float up = __shfl_xor(p[r + 2], 2, 64);
      float dn = __shfl_xor(p[r], 2, 64);
      p[r] = (lane & 2) ? (p[r + 2] + up) : (p[r] + dn);
    }
    {
      float up = __shfl_xor(p[1], 1, 64);
      float dn = __shfl_xor(p[0], 1, 64);
      p[0] = (lane & 1) ? (p[1] + up) : (p[0] + dn);
    }
    p[0] += __shfl_xor(p[0], 8, 64);
    p[0] += __shfl_xor(p[0], 16, 64);
    p[0] += __shfl_xor(p[0], 32, 64);
    if (lane < RB) red[wid * RB + lane] = p[0];  // red[w*8 + row]

    uint4 h;
    __half2 h01 = __floats2half2_rn(g * v[0], g * v[1]);
    __half2 h23 = __floats2half2_rn(g * v[2], g * v[3]);
    __half2 h45 = __floats2half2_rn(g * v[4], g * v[5]);
    __half2 h67 = __floats2half2_rn(g * v[6], g * v[7]);
    h.x = *reinterpret_cast<unsigned*>(&h01);
    h.y = *reinterpret_cast<unsigned*>(&h23);
    h.z = *reinterpret_cast<unsigned*>(&h45);
    h.w = *reinterpret_cast<unsigned*>(&h67);
    h_lds[swz((unsigned)tid)] = h;         // conflict-free under swz
  }  // v, p dead here

  __syncthreads();                          // barrier #1

  // every wave redundantly folds the 16 wave-partials and writes the SAME
  // rs_sh[0..7]; own-wave program order guarantees visibility at the epilogue.
  {
    float a = red[lane] + red[64 + lane];   // red[w*8+row]: w = lane>>3, 8+(lane>>3)
    a += __shfl_xor(a, 8, 64);
    a += __shfl_xor(a, 16, 64);
    a += __shfl_xor(a, 32, 64);
    if (lane < RB) rs_sh[lane] = rsqrtf(a * (1.0f / FDIM) + EPSV);
  }

  // ---------- Stage 1: acc = gather(g*x)·w1 (f16 packed) ----------
  __half2 acc2[4];
  {
    unsigned z = 0;
    #pragma unroll
    for (int d = 0; d < 4; ++d) acc2[d] = *reinterpret_cast<__half2*>(&z);
  }

  if (TR) {
    #pragma unroll
    for (int gk = 0; gk < 4; ++gk) {
      unsigned u[8];                        // transient: 8 loads in flight
      #pragma unroll
      for (int j = 0; j < 8; ++j) u[j] = pr1[(gk * 8 + j) * FDIM + o];
      #pragma unroll
      for (int j = 0; j < 8; ++j) gatherh(u[j], h_lds, acc2);
    }
  } else {
    #pragma unroll 8
    for (int k = 0; k < KNZ; ++k) {
      unsigned off = swz((unsigned)idx[o * KNZ + k]);
      unsigned e = (f16bits(w1[o * KNZ + k]) << 16) | off;
      gatherh(e, h_lds, acc2);
    }
  }

  // epilogue 1: z = rs*acc + b1 ; s = amp*sin(freq z)*exp(-decay z^2)
  {
    const float bb1 = b1[o], am = amp[o], fq = freq[o], dc = decay[o];
    const float4 ra = *reinterpret_cast<const float4*>(&rs_sh[0]);  // broadcast
    const float4 rb = *reinterpret_cast<const float4*>(&rs_sh[4]);
    const float rsv[RB] = {ra.x, ra.y, ra.z, ra.w, rb.x, rb.y, rb.z, rb.w};
    float accf[RB];
    #pragma unroll
    for (int d = 0; d < 4; ++d) {
      float2 f = __half22float2(acc2[d]);
      accf[2 * d] = f.x; accf[2 * d + 1] = f.y;
    }
    float s[RB];
    #pragma unroll
    for (int r = 0; r < RB; ++r) {
      float z = fmaf(accf[r], rsv[r], bb1);
      s[r] = am * __sinf(fq * z) * __expf(-dc * z * z);
    }
    uint4 sv;
    __half2 s01 = __floats2half2_rn(s[0], s[1]);
    __half2 s23 = __floats2half2_rn(s[2], s[3]);
    __half2 s45 = __floats2half2_rn(s[4], s[5]);
    __half2 s67 = __floats2half2_rn(s[6], s[7]);
    sv.x = *reinterpret_cast<unsigned*>(&s01);
    sv.y = *reinterpret_cast<unsigned*>(&s23);
    sv.z = *reinterpret_cast<unsigned*>(&s45);
    sv.w = *reinterpret_cast<unsigned*>(&s67);
    s_lds[swz((unsigned)o)] = sv;          // conflict-free under swz
  }
  __syncthreads();                          // barrier #2

  // ---------- Stage 2: h2 = gather(s)·w2 + b2 ; out = x + alpha*h2 ----------
  {
    unsigned z = 0;
    #pragma unroll
    for (int d = 0; d < 4; ++d) acc2[d] = *reinterpret_cast<__half2*>(&z);
  }

  if (TR) {
    #pragma unroll
    for (int gk = 0; gk < 4; ++gk) {
      unsigned u[8];
      #pragma unroll
      for (int j = 0; j < 8; ++j) u[j] = pr2[(gk * 8 + j) * FDIM + o];
      #pragma unroll
      for (int j = 0; j < 8; ++j) gatherh(u[j], s_lds, acc2);
    }
  } else {
    #pragma unroll 8
    for (int k = 0; k < KNZ; ++k) {
      unsigned off = swz((unsigned)idx[o * KNZ + k]);
      unsigned e = (f16bits(w2[o * KNZ + k]) << 16) | off;
      gatherh(e, s_lds, acc2);
    }
  }

  {
    const float bb2 = b2[o];
    const float al = alpha[0];
    float accf[RB];
    #pragma unroll
    for (int d = 0; d < 4; ++d) {
      float2 f = __half22float2(acc2[d]);
      accf[2 * d] = f.x; accf[2 * d + 1] = f.y;
    }
    #pragma unroll
    for (int r = 0; r < RB; ++r)
      out[(r0 + r) * FDIM + o] =
          fmaf(al, accf[r] + bb2, x[(r0 + r) * FDIM + o]);  // x re-read: L2-warm
  }
}

extern "C" void kernel_launch(void* const* d_in, const int* in_sizes, int n_in,
                              void* d_out, int out_size, void* d_ws, size_t ws_size,
                              hipStream_t stream) {
  const float* x      = (const float*)d_in[0];
  const int*   idx    = (const int*)d_in[1];
  const float* norm_w = (const float*)d_in[2];
  const float* w1     = (const float*)d_in[3];
  const float* b1     = (const float*)d_in[4];
  const float* amp    = (const float*)d_in[5];
  const float* freq   = (const float*)d_in[6];
  const float* decay  = (const float*)d_in[7];
  const float* w2     = (const float*)d_in[8];
  const float* b2     = (const float*)d_in[9];
  const float* alpha  = (const float*)d_in[10];
  float* out = (float*)d_out;

  const size_t need = 2ull * FDIM * KNZ * sizeof(unsigned);  // 256 KB
  if (ws_size >= need) {
    unsigned* pr1 = (unsigned*)d_ws;
    unsigned* pr2 = pr1 + (size_t)FDIM * KNZ;
    geo_prep<<<FDIM / 8, 256, 0, stream>>>(idx, w1, w2, pr1, pr2);
    geo_main<true><<<NROWS / RB, TPB, 0, stream>>>(
        x, norm_w, b1, amp, freq, decay, b2, alpha, pr1, pr2, idx, w1, w2, out);
  } else {
    geo_main<false><<<NROWS / RB, TPB, 0, stream>>>(
        x, norm_w, b1, amp, freq, decay, b2, alpha, nullptr, nullptr, idx, w1, w2, out);
  }
}